// Round 8
// baseline (920.284 us; speedup 1.0000x reference)
//
#include <hip/hip_runtime.h>

#define B_ 32
#define T_ 24
#define N_ 2048
#define D_ 64
#define K_ 32
#define H_ 16
#define NB 16

typedef __attribute__((ext_vector_type(8))) short bf16x8;
typedef __attribute__((ext_vector_type(4))) float f32x4;

__device__ __forceinline__ unsigned short f2bf(float f) {
    unsigned int u = __float_as_uint(f);
    return (unsigned short)((u + 0x7FFFu + ((u >> 16) & 1u)) >> 16);
}
__device__ __forceinline__ float bf2f(unsigned short h) {
    return __uint_as_float(((unsigned int)h) << 16);
}

// M2 (bf16), block-sliced: M2[n>>4][t][n&15][t2] = sum_h ad[h][t]*ad[h][t2]
__global__ void k_prepM(const float* __restrict__ ne, const float* __restrict__ adj,
                        unsigned short* __restrict__ M2) {
    __shared__ float s_ne[K_];
    __shared__ float s_ad[H_ * T_];
    const int n = blockIdx.x;
    const int tid = threadIdx.x;  // 64 threads
    if (tid < K_) s_ne[tid] = ne[n * K_ + tid];
    __syncthreads();
    for (int f = tid; f < H_ * T_; f += 64) {
        const int h = f / T_, t = f % T_;
        float a = 0.f;
#pragma unroll
        for (int k = 0; k < K_; ++k) a += s_ne[k] * adj[(k * H_ + h) * T_ + t];
        s_ad[f] = a;
    }
    __syncthreads();
    unsigned short* dst = M2 + (size_t)(n >> 4) * (T_ * T_ * 16) + (n & 15) * T_;
    for (int m = tid; m < T_ * T_; m += 64) {
        const int t = m / T_, t2 = m % T_;
        float a = 0.f;
#pragma unroll
        for (int h = 0; h < H_; ++h) a += s_ad[h * T_ + t] * s_ad[h * T_ + t2];
        dst[t * (16 * T_) + t2] = f2bf(a);
    }
}

// Wt[bt][o][i] (bf16) = sum_k te[bt][k]*wp[k][i][o];  bias[bt][o] f32
__global__ __launch_bounds__(256) void k_prepW(const float* __restrict__ te,
                                               const float* __restrict__ wp,
                                               const float* __restrict__ bp,
                                               unsigned short* __restrict__ Wt,
                                               float* __restrict__ bias) {
    const int bt = blockIdx.x;   // 0..B*T-1
    const int tid = threadIdx.x; // 256
    __shared__ float s_te[K_];
    __shared__ float s_W[D_ * D_];  // [i][o] f32
    if (tid < K_) s_te[tid] = te[bt * K_ + tid];
    __syncthreads();
    float4 acc[4] = {};
    for (int k = 0; k < K_; ++k) {
        const float tk = s_te[k];
        const float4* row = (const float4*)(wp + (size_t)k * (D_ * D_));
#pragma unroll
        for (int i = 0; i < 4; ++i) {
            float4 v = row[tid + i * 256];
            acc[i].x += tk * v.x; acc[i].y += tk * v.y;
            acc[i].z += tk * v.z; acc[i].w += tk * v.w;
        }
    }
    float4* sW4 = (float4*)s_W;
#pragma unroll
    for (int i = 0; i < 4; ++i) sW4[tid + i * 256] = acc[i];
    if (tid < D_) {
        float a = 0.f;
#pragma unroll
        for (int k = 0; k < K_; ++k) a += s_te[k] * bp[k * D_ + tid];
        bias[bt * D_ + tid] = a;
    }
    __syncthreads();
    // transpose -> bf16: Wt[o][i]
    const int o = tid >> 2;
    const int i0 = (tid & 3) * 16;
    unsigned short* dst = Wt + (size_t)bt * (D_ * D_) + o * D_ + i0;
#pragma unroll
    for (int j = 0; j < 16; j += 4) {
        ushort4 u;
        u.x = f2bf(s_W[(i0 + j + 0) * D_ + o]);
        u.y = f2bf(s_W[(i0 + j + 1) * D_ + o]);
        u.z = f2bf(s_W[(i0 + j + 2) * D_ + o]);
        u.w = f2bf(s_W[(i0 + j + 3) * D_ + o]);
        *(ushort4*)(dst + j) = u;
    }
}

// chunk of 8 tp's: M frags are named bf16x8 vars (static), eb via base+imm-offset
#define MIXC(MV0, MV1, MV2, CB)                                        \
    _Pragma("unroll")                                                  \
    for (int j = 0; j < 8; ++j) {                                      \
        const int tp = (CB) + j;                                       \
        const bf16x8 e0 = *(const bf16x8*)(base0 + tp * 2048);         \
        const bf16x8 e1 = *(const bf16x8*)(base1 + tp * 2048);         \
        const float f0 = bf2f((unsigned short)MV0[j]);                 \
        const float f1 = bf2f((unsigned short)MV1[j]);                 \
        const float f2 = bf2f((unsigned short)MV2[j]);                 \
        _Pragma("unroll")                                              \
        for (int q = 0; q < 8; ++q) {                                  \
            const float ea = bf2f((unsigned short)e0[q]);              \
            const float eb2 = bf2f((unsigned short)e1[q]);             \
            acc[0][q] += f0 * ea; acc[0][8 + q] += f0 * eb2;           \
            acc[1][q] += f1 * ea; acc[1][8 + q] += f1 * eb2;           \
            acc[2][q] += f2 * ea; acc[2][8 + q] += f2 * eb2;           \
        }                                                              \
    }

// Fused: mix (VALU, M+eb from LDS) -> MFMA vs Wt -> epilogue.
// Block = (16-node tile, b), 512 threads / 8 waves; wave w owns t in [3w, 3w+3).
__global__ __launch_bounds__(512, 4) void k_fused(const float* __restrict__ eb,
                                                  const unsigned short* __restrict__ M2,
                                                  const unsigned short* __restrict__ Wt,
                                                  const float* __restrict__ bias,
                                                  float* __restrict__ out) {
    const int b = blockIdx.y;
    const int nb = blockIdx.x * NB;
    const int tid = threadIdx.x;
    const int wave = tid >> 6, lane = tid & 63;
    const int lr = lane & 15, lh = lane >> 4;

    __shared__ unsigned short s_eb[T_ * NB * D_];   // 49152 B, [t][n][d] swizzled
    __shared__ unsigned short s_M[T_ * NB * 26];    // 19968 B, [t][n][26] (24 used, pad 26)

    // ---- stage eb[b][:][nb:nb+16][:] -> LDS bf16 (512 threads, 12 float4 each) ----
    {
        const float* ebb = eb + (size_t)(b * T_) * N_ * D_;
#pragma unroll
        for (int it = 0; it < 12; ++it) {
            const int f4 = it * 512 + tid;
            const int t = f4 >> 8;
            const int n = (f4 >> 4) & 15;
            const int d0 = (f4 & 15) * 4;
            const float4 v = *(const float4*)(ebb + ((size_t)t * N_ + nb + n) * D_ + d0);
            ushort4 u;
            u.x = f2bf(v.x); u.y = f2bf(v.y); u.z = f2bf(v.z); u.w = f2bf(v.w);
            const int inrow = (d0 * 2) ^ ((n & 7) << 4);
            *(ushort4*)((char*)s_eb + t * (NB * 128) + n * 128 + inrow) = u;
        }
    }
    // ---- stage M block slice -> LDS (pad 24->26 for conflict-free b128 reads) ----
    {
        const unsigned short* Mblk = M2 + (size_t)blockIdx.x * (T_ * T_ * 16);
#pragma unroll
        for (int it = 0; it < 18; ++it) {
            const int e = it * 512 + tid;   // e < 9216
            const int t = e / (16 * T_);
            const int rem = e - t * (16 * T_);
            const int n = rem / T_;
            const int tp = rem - n * T_;
            s_M[(t * 16 + n) * 26 + tp] = Mblk[e];
        }
    }
    __syncthreads();

    const char* ebase = (const char*)s_eb;
    const int sw = (lr & 7) << 4;
    const int tb = wave * 3;

    // M fragments: 9 x ds_read_b128, conflict-free (row stride 52B -> 13 banks)
    const char* mbase = (const char*)s_M + (tb * 16 + lr) * 52;
    const bf16x8 m0c0 = *(const bf16x8*)(mbase + 0 * 832 + 0);
    const bf16x8 m0c1 = *(const bf16x8*)(mbase + 0 * 832 + 16);
    const bf16x8 m0c2 = *(const bf16x8*)(mbase + 0 * 832 + 32);
    const bf16x8 m1c0 = *(const bf16x8*)(mbase + 1 * 832 + 0);
    const bf16x8 m1c1 = *(const bf16x8*)(mbase + 1 * 832 + 16);
    const bf16x8 m1c2 = *(const bf16x8*)(mbase + 1 * 832 + 32);
    const bf16x8 m2c0 = *(const bf16x8*)(mbase + 2 * 832 + 0);
    const bf16x8 m2c1 = *(const bf16x8*)(mbase + 2 * 832 + 16);
    const bf16x8 m2c2 = *(const bf16x8*)(mbase + 2 * 832 + 32);

    // eb bases: lane-constant, tp advances via immediate offset (tp*2048)
    const char* base0 = ebase + lr * 128 + ((lh * 16) ^ sw);
    const char* base1 = ebase + lr * 128 + ((((lh + 4) * 16)) ^ sw);

    float acc[3][16];
#pragma unroll
    for (int tt = 0; tt < 3; ++tt)
#pragma unroll
        for (int j = 0; j < 16; ++j) acc[tt][j] = 0.f;

    MIXC(m0c0, m1c0, m2c0, 0)
    MIXC(m0c1, m1c1, m2c1, 8)
    MIXC(m0c2, m1c2, m2c2, 16)

    // convert to MFMA A-fragments: lane holds ret[t][n=lr][lh*8+j] and [32+lh*8+j]
    bf16x8 Af[3][2];
#pragma unroll
    for (int tt = 0; tt < 3; ++tt)
#pragma unroll
        for (int j = 0; j < 8; ++j) {
            Af[tt][0][j] = (short)f2bf(acc[tt][j]);
            Af[tt][1][j] = (short)f2bf(acc[tt][8 + j]);
        }

#pragma unroll
    for (int tt = 0; tt < 3; ++tt) {
        const int t = tb + tt;
        const int bt = b * T_ + t;
        const unsigned short* Wb = Wt + (size_t)bt * (D_ * D_);
        f32x4 C[4] = {};
#pragma unroll
        for (int ot = 0; ot < 4; ++ot) {
            const bf16x8 B0 = *(const bf16x8*)(Wb + (ot * 16 + lr) * D_ + lh * 8);
            const bf16x8 B1 = *(const bf16x8*)(Wb + (ot * 16 + lr) * D_ + 32 + lh * 8);
            C[ot] = __builtin_amdgcn_mfma_f32_16x16x32_bf16(Af[tt][0], B0, C[ot], 0, 0, 0);
            C[ot] = __builtin_amdgcn_mfma_f32_16x16x32_bf16(Af[tt][1], B1, C[ot], 0, 0, 0);
        }
        float bv[4];
#pragma unroll
        for (int ot = 0; ot < 4; ++ot) bv[ot] = bias[bt * D_ + ot * 16 + lr];

        float* obt = out + ((size_t)bt * N_ + nb) * D_;
#pragma unroll
        for (int r = 0; r < 4; ++r) {
            const int nn = lh * 4 + r;  // node within tile (C-row)
            const char* erow = ebase + (t * NB + nn) * 128;
            const int swn = (nn & 7) << 4;
#pragma unroll
            for (int ot = 0; ot < 4; ++ot) {
                const int o = ot * 16 + lr;  // C-col
                const unsigned short eu =
                    *(const unsigned short*)(erow + ((o * 2) ^ swn));
                float v = C[ot][r] + bv[ot] + bf2f(eu);
                v = v >= 0.f ? v : 0.01f * v;
                obt[(size_t)nn * D_ + o] = v;
            }
        }
    }
}

extern "C" void kernel_launch(void* const* d_in, const int* in_sizes, int n_in,
                              void* d_out, int out_size, void* d_ws, size_t ws_size,
                              hipStream_t stream) {
    const float* eb  = (const float*)d_in[0];
    const float* ne  = (const float*)d_in[1];
    const float* te  = (const float*)d_in[2];
    const float* adj = (const float*)d_in[3];
    const float* wp  = (const float*)d_in[4];
    const float* bp  = (const float*)d_in[5];
    float* out = (float*)d_out;

    char* ws = (char*)d_ws;
    const size_t M_bytes  = (size_t)N_ * T_ * T_ * 2;       // 2,359,296 (bf16)
    const size_t Wt_bytes = (size_t)B_ * T_ * D_ * D_ * 2;  // 6,291,456
    unsigned short* M2 = (unsigned short*)ws;
    unsigned short* Wt = (unsigned short*)(ws + M_bytes);
    float* bias        = (float*)(ws + M_bytes + Wt_bytes);

    k_prepM<<<N_, 64, 0, stream>>>(ne, adj, M2);
    k_prepW<<<B_ * T_, 256, 0, stream>>>(te, wp, bp, Wt, bias);
    k_fused<<<dim3(N_ / NB, B_), 512, 0, stream>>>(eb, M2, Wt, bias, out);
}

// Round 9
// 284.558 us; speedup vs baseline: 3.2341x; 3.2341x over previous
//
#include <hip/hip_runtime.h>

#define B_ 32
#define T_ 24
#define N_ 2048
#define D_ 64
#define K_ 32
#define H_ 16
#define NB 16

typedef __attribute__((ext_vector_type(8))) short bf16x8;
typedef __attribute__((ext_vector_type(4))) float f32x4;

__device__ __forceinline__ unsigned short f2bf(float f) {
    unsigned int u = __float_as_uint(f);
    return (unsigned short)((u + 0x7FFFu + ((u >> 16) & 1u)) >> 16);
}
__device__ __forceinline__ float bf2f(unsigned short h) {
    return __uint_as_float(((unsigned int)h) << 16);
}

// M2 (bf16), block-sliced: flat = blk*9216 + t*384 + n*24 + t2
__global__ void k_prepM(const float* __restrict__ ne, const float* __restrict__ adj,
                        unsigned short* __restrict__ M2) {
    __shared__ float s_ne[K_];
    __shared__ float s_ad[H_ * T_];
    const int n = blockIdx.x;
    const int tid = threadIdx.x;  // 64 threads
    if (tid < K_) s_ne[tid] = ne[n * K_ + tid];
    __syncthreads();
    for (int f = tid; f < H_ * T_; f += 64) {
        const int h = f / T_, t = f % T_;
        float a = 0.f;
#pragma unroll
        for (int k = 0; k < K_; ++k) a += s_ne[k] * adj[(k * H_ + h) * T_ + t];
        s_ad[f] = a;
    }
    __syncthreads();
    unsigned short* dst = M2 + (size_t)(n >> 4) * (T_ * T_ * 16) + (n & 15) * T_;
    for (int m = tid; m < T_ * T_; m += 64) {
        const int t = m / T_, t2 = m % T_;
        float a = 0.f;
#pragma unroll
        for (int h = 0; h < H_; ++h) a += s_ad[h * T_ + t] * s_ad[h * T_ + t2];
        dst[t * (16 * T_) + t2] = f2bf(a);
    }
}

// Wt[bt][o][i] (bf16) = sum_k te[bt][k]*wp[k][i][o];  bias[bt][o] f32
__global__ __launch_bounds__(256) void k_prepW(const float* __restrict__ te,
                                               const float* __restrict__ wp,
                                               const float* __restrict__ bp,
                                               unsigned short* __restrict__ Wt,
                                               float* __restrict__ bias) {
    const int bt = blockIdx.x;   // 0..B*T-1
    const int tid = threadIdx.x; // 256
    __shared__ float s_te[K_];
    __shared__ float s_W[D_ * D_];  // [i][o] f32
    if (tid < K_) s_te[tid] = te[bt * K_ + tid];
    __syncthreads();
    float4 acc[4] = {};
    for (int k = 0; k < K_; ++k) {
        const float tk = s_te[k];
        const float4* row = (const float4*)(wp + (size_t)k * (D_ * D_));
#pragma unroll
        for (int i = 0; i < 4; ++i) {
            float4 v = row[tid + i * 256];
            acc[i].x += tk * v.x; acc[i].y += tk * v.y;
            acc[i].z += tk * v.z; acc[i].w += tk * v.w;
        }
    }
    float4* sW4 = (float4*)s_W;
#pragma unroll
    for (int i = 0; i < 4; ++i) sW4[tid + i * 256] = acc[i];
    if (tid < D_) {
        float a = 0.f;
#pragma unroll
        for (int k = 0; k < K_; ++k) a += s_te[k] * bp[k * D_ + tid];
        bias[bt * D_ + tid] = a;
    }
    __syncthreads();
    // transpose -> bf16: Wt[o][i]
    const int o = tid >> 2;
    const int i0 = (tid & 3) * 16;
    unsigned short* dst = Wt + (size_t)bt * (D_ * D_) + o * D_ + i0;
#pragma unroll
    for (int j = 0; j < 16; j += 4) {
        ushort4 u;
        u.x = f2bf(s_W[(i0 + j + 0) * D_ + o]);
        u.y = f2bf(s_W[(i0 + j + 1) * D_ + o]);
        u.z = f2bf(s_W[(i0 + j + 2) * D_ + o]);
        u.w = f2bf(s_W[(i0 + j + 3) * D_ + o]);
        *(ushort4*)(dst + j) = u;
    }
}

// Fused: mix (VALU; M scalar ds_reads + eb b128 ds_reads) -> MFMA vs Wt -> epilogue.
// Block = (16-node tile, b), 512 threads / 8 waves; wave w owns t in [3w, 3w+3).
// launch_bounds(512,2): 2 blocks/CU -> 4 waves/SIMD, VGPR cap 128 (no spill).
__global__ __launch_bounds__(512, 2) void k_fused(const float* __restrict__ eb,
                                                  const unsigned short* __restrict__ M2,
                                                  const unsigned short* __restrict__ Wt,
                                                  const float* __restrict__ bias,
                                                  float* __restrict__ out) {
    const int b = blockIdx.y;
    const int nb = blockIdx.x * NB;
    const int tid = threadIdx.x;
    const int wave = tid >> 6, lane = tid & 63;
    const int lr = lane & 15, lh = lane >> 4;

    __shared__ unsigned short s_eb[T_ * NB * D_];   // 49152 B, [t][n][d] swizzled
    __shared__ unsigned short s_M[T_ * NB * T_];    // 18432 B, [t][n][tp] linear

    // ---- stage eb[b][:][nb:nb+16][:] -> LDS bf16 (512 threads, 12 float4 each) ----
    {
        const float* ebb = eb + (size_t)(b * T_) * N_ * D_;
#pragma unroll
        for (int it = 0; it < 12; ++it) {
            const int f4 = it * 512 + tid;
            const int t = f4 >> 8;
            const int n = (f4 >> 4) & 15;
            const int d0 = (f4 & 15) * 4;
            const float4 v = *(const float4*)(ebb + ((size_t)t * N_ + nb + n) * D_ + d0);
            ushort4 u;
            u.x = f2bf(v.x); u.y = f2bf(v.y); u.z = f2bf(v.z); u.w = f2bf(v.w);
            const int inrow = (d0 * 2) ^ ((n & 7) << 4);
            *(ushort4*)((char*)s_eb + t * (NB * 128) + n * 128 + inrow) = u;
        }
    }
    // ---- stage M block slice -> LDS: linear copy (layout already [t][n][tp]) ----
    {
        const unsigned short* Mblk = M2 + (size_t)blockIdx.x * (T_ * T_ * 16);
#pragma unroll
        for (int it = 0; it < 18; ++it) {
            const int e = it * 512 + tid;   // e < 9216
            s_M[e] = Mblk[e];
        }
    }
    __syncthreads();

    const char* ebase = (const char*)s_eb;
    const int sw = (lr & 7) << 4;
    const int tb = wave * 3;

    // lane-constant bases; tp advances via immediate offsets
    const unsigned short* mrow = s_M + tb * (16 * T_) + lr * T_;  // rows t=tb..tb+2 at +384,+768
    const char* base0 = ebase + lr * 128 + ((lh * 16) ^ sw);
    const char* base1 = ebase + lr * 128 + ((((lh + 4) * 16)) ^ sw);

    float acc[3][16];
#pragma unroll
    for (int tt = 0; tt < 3; ++tt)
#pragma unroll
        for (int j = 0; j < 16; ++j) acc[tt][j] = 0.f;

#pragma unroll
    for (int tp = 0; tp < T_; ++tp) {
        const float m0 = bf2f(mrow[tp]);
        const float m1 = bf2f(mrow[384 + tp]);
        const float m2 = bf2f(mrow[768 + tp]);
        const bf16x8 e0 = *(const bf16x8*)(base0 + tp * 2048);
        const bf16x8 e1 = *(const bf16x8*)(base1 + tp * 2048);
#pragma unroll
        for (int q = 0; q < 8; ++q) {
            const float ea = bf2f((unsigned short)e0[q]);
            const float eb2 = bf2f((unsigned short)e1[q]);
            acc[0][q] += m0 * ea; acc[0][8 + q] += m0 * eb2;
            acc[1][q] += m1 * ea; acc[1][8 + q] += m1 * eb2;
            acc[2][q] += m2 * ea; acc[2][8 + q] += m2 * eb2;
        }
    }

    // convert to MFMA A-fragments: lane holds ret[t][n=lr][lh*8+j] and [32+lh*8+j]
    bf16x8 Af[3][2];
#pragma unroll
    for (int tt = 0; tt < 3; ++tt)
#pragma unroll
        for (int j = 0; j < 8; ++j) {
            Af[tt][0][j] = (short)f2bf(acc[tt][j]);
            Af[tt][1][j] = (short)f2bf(acc[tt][8 + j]);
        }

#pragma unroll
    for (int tt = 0; tt < 3; ++tt) {
        const int t = tb + tt;
        const int bt = b * T_ + t;
        const unsigned short* Wb = Wt + (size_t)bt * (D_ * D_);
        f32x4 C[4] = {};
#pragma unroll
        for (int ot = 0; ot < 4; ++ot) {
            const bf16x8 B0 = *(const bf16x8*)(Wb + (ot * 16 + lr) * D_ + lh * 8);
            const bf16x8 B1 = *(const bf16x8*)(Wb + (ot * 16 + lr) * D_ + 32 + lh * 8);
            C[ot] = __builtin_amdgcn_mfma_f32_16x16x32_bf16(Af[tt][0], B0, C[ot], 0, 0, 0);
            C[ot] = __builtin_amdgcn_mfma_f32_16x16x32_bf16(Af[tt][1], B1, C[ot], 0, 0, 0);
        }
        float bv[4];
#pragma unroll
        for (int ot = 0; ot < 4; ++ot) bv[ot] = bias[bt * D_ + ot * 16 + lr];

        float* obt = out + ((size_t)bt * N_ + nb) * D_;
#pragma unroll
        for (int r = 0; r < 4; ++r) {
            const int nn = lh * 4 + r;  // node within tile (C-row)
            const char* erow = ebase + (t * NB + nn) * 128;
            const int swn = (nn & 7) << 4;
#pragma unroll
            for (int ot = 0; ot < 4; ++ot) {
                const int o = ot * 16 + lr;  // C-col
                const unsigned short eu =
                    *(const unsigned short*)(erow + ((o * 2) ^ swn));
                float v = C[ot][r] + bv[ot] + bf2f(eu);
                v = v >= 0.f ? v : 0.01f * v;
                obt[(size_t)nn * D_ + o] = v;
            }
        }
    }
}

extern "C" void kernel_launch(void* const* d_in, const int* in_sizes, int n_in,
                              void* d_out, int out_size, void* d_ws, size_t ws_size,
                              hipStream_t stream) {
    const float* eb  = (const float*)d_in[0];
    const float* ne  = (const float*)d_in[1];
    const float* te  = (const float*)d_in[2];
    const float* adj = (const float*)d_in[3];
    const float* wp  = (const float*)d_in[4];
    const float* bp  = (const float*)d_in[5];
    float* out = (float*)d_out;

    char* ws = (char*)d_ws;
    const size_t M_bytes  = (size_t)N_ * T_ * T_ * 2;       // 2,359,296 (bf16)
    const size_t Wt_bytes = (size_t)B_ * T_ * D_ * D_ * 2;  // 6,291,456
    unsigned short* M2 = (unsigned short*)ws;
    unsigned short* Wt = (unsigned short*)(ws + M_bytes);
    float* bias        = (float*)(ws + M_bytes + Wt_bytes);

    k_prepM<<<N_, 64, 0, stream>>>(ne, adj, M2);
    k_prepW<<<B_ * T_, 256, 0, stream>>>(te, wp, bp, Wt, bias);
    k_fused<<<dim3(N_ / NB, B_), 512, 0, stream>>>(eb, M2, Wt, bias, out);
}